// Round 4
// baseline (2717.204 us; speedup 1.0000x reference)
//
#include <hip/hip_runtime.h>

#define B_TOK 32768
#define D_IN  256
#define H_LAT 8192
#define TOPK  32
#define MT    64          // rows per block
#define NT    128         // h-cols per chunk
#define NCH   (H_LAT / NT)
#define KC    64          // k-slice per stage
#define CAP   144         // candidate pool per row (thr=2.3sigma -> lambda~88; 6-sigma headroom)
#define XS    264         // xbf row stride (ushort), 132 dw
#define WS_   72          // wt row stride (ushort), 36 dw
#define DELTA 0.016f      // rescore window half-width; bf16-GEMM boundary err <= ~4.5e-3 -> delta >= 2*eps

typedef __attribute__((ext_vector_type(4))) float f32x4;
typedef __attribute__((ext_vector_type(8))) short bf16x8;

__device__ __forceinline__ unsigned short f2bf(float f) {   // RNE fp32->bf16
    unsigned u = __float_as_uint(f);
    return (unsigned short)((u + 0x7fffu + ((u >> 16) & 1u)) >> 16);
}

// Kernel A: W_enc fp32 -> bf16 into ws; also reduce sum(W^2) -> ws scalar.
__global__ __launch_bounds__(256)
void conv_kernel(const float* __restrict__ W, unsigned short* __restrict__ Wbf,
                 float* __restrict__ s2w) {
    const int total4 = (H_LAT * D_IN) / 4;
    float acc = 0.0f;
    for (int i = blockIdx.x * blockDim.x + threadIdx.x; i < total4;
         i += gridDim.x * blockDim.x) {
        const float4 v = ((const float4*)W)[i];
        acc += v.x * v.x + v.y * v.y + v.z * v.z + v.w * v.w;
        ushort4 o;
        o.x = f2bf(v.x); o.y = f2bf(v.y); o.z = f2bf(v.z); o.w = f2bf(v.w);
        ((ushort4*)Wbf)[i] = o;
    }
#pragma unroll
    for (int off = 32; off > 0; off >>= 1) acc += __shfl_down(acc, off, 64);
    if ((threadIdx.x & 63) == 0) atomicAdd(s2w, acc);
}

// Kernel B: bf16-MFMA filter -> pool -> wave-parallel rank-count top-64 ->
// exact fp32 rescore (selected + boundary window) -> final rank top-32 -> decoder.
__global__ __launch_bounds__(256, 1)
void sae_main(const float* __restrict__ x, const float* __restrict__ W_enc,
              const float* __restrict__ b_enc, const float* __restrict__ W_dec,
              const float* __restrict__ b_dec, float* __restrict__ out,
              const unsigned short* __restrict__ Wbf, const float* __restrict__ s2w) {
    __shared__ __align__(16) unsigned short xbf[MT][XS];        // 33792 B
    __shared__ __align__(16) unsigned short wt[NT][WS_];        // 18432 B
    __shared__ float          pool_v[MT][CAP];                  // 36864 B
    __shared__ unsigned short pool_i[MT][CAP];                  // 18432 B
    __shared__ float          ext_v[MT][64];                    // 16384 B
    __shared__ unsigned short ext_i[MT][64];                    //  8192 B
    __shared__ int   cnt[MT];
    __shared__ float thr[MT];

    const int tid  = threadIdx.x;
    const int row0 = blockIdx.x * MT;
    const int wave = tid >> 6, lane = tid & 63;
    const int l15 = lane & 15, quad = lane >> 4;

    if (tid < MT) { cnt[tid] = 0; thr[tid] = 0.0f; }
    __syncthreads();

    // ---- Phase 0: stage (x - b_dec) -> bf16 LDS; per-row sum(x^2) ----
    {
        const int r = tid >> 2, q = tid & 3;                    // 4 threads/row, 64 k each
        const float* xr = x + (size_t)(row0 + r) * D_IN + q * 64;
        const float* bd = b_dec + q * 64;
        float s2 = 0.0f;
#pragma unroll
        for (int j = 0; j < 8; ++j) {
            const float4 a = ((const float4*)xr)[2 * j];
            const float4 b = ((const float4*)xr)[2 * j + 1];
            const float4 da = ((const float4*)bd)[2 * j];
            const float4 db = ((const float4*)bd)[2 * j + 1];
            float v[8] = {a.x - da.x, a.y - da.y, a.z - da.z, a.w - da.w,
                          b.x - db.x, b.y - db.y, b.z - db.z, b.w - db.w};
            ushort4 p0, p1;
            p0.x = f2bf(v[0]); p0.y = f2bf(v[1]); p0.z = f2bf(v[2]); p0.w = f2bf(v[3]);
            p1.x = f2bf(v[4]); p1.y = f2bf(v[5]); p1.z = f2bf(v[6]); p1.w = f2bf(v[7]);
#pragma unroll
            for (int e = 0; e < 8; ++e) s2 += v[e] * v[e];
            *(ushort4*)&xbf[r][q * 64 + j * 8]     = p0;
            *(ushort4*)&xbf[r][q * 64 + j * 8 + 4] = p1;
        }
        atomicAdd(&thr[r], s2);
    }
    __syncthreads();
    if (tid < MT) {
        const float s2wm = s2w[0] * (1.0f / ((float)H_LAT * (float)D_IN));
        thr[tid] = 2.3f * sqrtf(s2wm * thr[tid]);
    }
    __syncthreads();

    // per-lane thresholds for the 16 (mt,qi) rows this lane's acc covers
    float thrv[4][4];
#pragma unroll
    for (int mt = 0; mt < 4; ++mt)
#pragma unroll
        for (int qi = 0; qi < 4; ++qi) thrv[mt][qi] = thr[mt * 16 + quad * 4 + qi];

    // ---- Phase 1: MFMA filter GEMM (wave owns a 32-col strip) + collection ----
    const int colbase = wave * 32;
    const int wrow = tid >> 1, half = tid & 1;                  // staging map
    int4 wreg[4];
    {   // prologue: prefetch (nc=0, kc=0)
        const unsigned short* src = Wbf + (size_t)wrow * D_IN + half * 32;
#pragma unroll
        for (int j = 0; j < 4; ++j) wreg[j] = *(const int4*)(src + j * 8);
    }

    for (int nc = 0; nc < NCH; ++nc) {
        const int h0 = nc * NT;
        f32x4 acc[4][2];
#pragma unroll
        for (int mt = 0; mt < 4; ++mt)
#pragma unroll
            for (int ct = 0; ct < 2; ++ct) acc[mt][ct] = {0.f, 0.f, 0.f, 0.f};

        for (int kc = 0; kc < D_IN / KC; ++kc) {
            __syncthreads();                                    // prior readers of wt done
            {   // commit staged regs
                unsigned short* dst = &wt[wrow][half * 32];
#pragma unroll
                for (int j = 0; j < 4; ++j) *(int4*)(dst + j * 8) = wreg[j];
            }
            __syncthreads();                                    // wt ready
            // issue next-tile global loads NOW -> they fly during the MFMAs below
            {
                int nkc = kc + 1, nnc = nc;
                if (nkc == 4) { nkc = 0; nnc = nc + 1; }
                if (nnc < NCH) {
                    const unsigned short* src =
                        Wbf + (size_t)(nnc * NT + wrow) * D_IN + nkc * KC + half * 32;
#pragma unroll
                    for (int j = 0; j < 4; ++j) wreg[j] = *(const int4*)(src + j * 8);
                }
            }
            // MFMA: 4 m-tiles x 2 col-tiles, K=64 (2 mfma each)
            bf16x8 a0[4], a1[4];
#pragma unroll
            for (int mt = 0; mt < 4; ++mt) {
                a0[mt] = *(const bf16x8*)&xbf[mt * 16 + l15][kc * KC + quad * 8];
                a1[mt] = *(const bf16x8*)&xbf[mt * 16 + l15][kc * KC + 32 + quad * 8];
            }
#pragma unroll
            for (int ct = 0; ct < 2; ++ct) {
                const int wr = colbase + ct * 16 + l15;
                const bf16x8 b0 = *(const bf16x8*)&wt[wr][quad * 8];
                const bf16x8 b1 = *(const bf16x8*)&wt[wr][32 + quad * 8];
#pragma unroll
                for (int mt = 0; mt < 4; ++mt) {
                    acc[mt][ct] = __builtin_amdgcn_mfma_f32_16x16x32_bf16(a0[mt], b0, acc[mt][ct], 0, 0, 0);
                    acc[mt][ct] = __builtin_amdgcn_mfma_f32_16x16x32_bf16(a1[mt], b1, acc[mt][ct], 0, 0, 0);
                }
            }
        }
        // collection (C/D: col=lane&15, row=quad*4+reg)
#pragma unroll
        for (int ct = 0; ct < 2; ++ct) {
            const int col = h0 + colbase + ct * 16 + l15;
            const float bv = b_enc[col];
#pragma unroll
            for (int mt = 0; mt < 4; ++mt)
#pragma unroll
                for (int qi = 0; qi < 4; ++qi) {
                    const float v = acc[mt][ct][qi] + bv;
                    if (v > thrv[mt][qi]) {
                        const int r = mt * 16 + quad * 4 + qi;
                        const int pos = atomicAdd(&cnt[r], 1);
                        if (pos < CAP) { pool_v[r][pos] = v; pool_i[r][pos] = (unsigned short)col; }
                    }
                }
        }
    }
    __syncthreads();    // pools complete

    // ---- Phase 2: wave-parallel rank-count -> sorted top-64 approx into ext ----
    {
        const int rbase = wave * 16;
        for (int rr = 0; rr < 16; ++rr) {
            const int r = rbase + rr;
            const int n = min(cnt[r], CAP);
            const int S = (n <= 64) ? 1 : (n <= 128 ? 2 : 3);   // wave-uniform
            float v[3]; int h[3]; int rank[3] = {0, 0, 0};
#pragma unroll
            for (int e = 0; e < 3; ++e) {
                const int c = e * 64 + lane;
                if (c < n) { v[e] = pool_v[r][c]; h[e] = pool_i[r][c]; }
                else       { v[e] = -1.0f;        h[e] = H_LAT + c; }   // unique empty keys
            }
            for (int s = 0; s < 64; ++s) {
                const int src = (lane + s) & 63;
                for (int e = 0; e < S; ++e) {
                    const float wv = __shfl(v[e], src, 64);
                    const int   wh = __shfl(h[e], src, 64);
                    for (int a = 0; a < S; ++a)
                        rank[a] += (wv > v[a]) || (wv == v[a] && wh < h[a]);
                }
            }
            for (int a = 0; a < S; ++a)
                if (rank[a] < 64) { ext_v[r][rank[a]] = v[a]; ext_i[r][rank[a]] = (unsigned short)h[a]; }
        }
    }
    __syncthreads();

    // ---- Phase 3: exact fp32 rescore (selected + boundary window), parallel ----
    {
        const int r = tid & 63, c = tid >> 6;                   // 4 threads/row, j = 4k+c
        const float cut = ext_v[r][TOPK - 1] - DELTA;           // approx v32 - delta
        __syncthreads();                                        // everyone read v32 before writes
        const float* xr = x + (size_t)(row0 + r) * D_IN;
        for (int k = 0; k < 16; ++k) {
            const int j = 4 * k + c;
            const float v = ext_v[r][j];
            if (v > 0.0f && (j < TOPK || v >= cut)) {
                const int h = ext_i[r][j];
                const float* wr = W_enc + (size_t)h * D_IN;
                float s = 0.0f;
                for (int kk = 0; kk < D_IN; ++kk)               // serial fmaf == np oracle
                    s = fmaf(xr[kk] - b_dec[kk], wr[kk], s);
                s += b_enc[h];
                ext_v[r][j] = fmaxf(s, 0.0f);
            }
        }
    }
    __syncthreads();

    // ---- Phase 4: final rank (exact values) -> top-32 -> decoder, wave-local ----
    {
        const int rbase = wave * 16;
        const float4 bd4 = *(const float4*)&b_dec[lane * 4];
        for (int rr = 0; rr < 16; ++rr) {
            const int r = rbase + rr;
            const float v = ext_v[r][lane];
            const int   h = ext_i[r][lane];
            int rank = 0;
            for (int s = 0; s < 64; ++s) {
                const int src = (lane + s) & 63;
                const float wv = __shfl(v, src, 64);
                const int   wh = __shfl(h, src, 64);
                rank += (wv > v) || (wv == v && wh < h);
            }
            if (rank < TOPK) { ext_v[r][rank] = v; ext_i[r][rank] = (unsigned short)h; }
            // decoder for this row (ranks 0..31 are a permutation -> all written)
            float4 o = bd4;
#pragma unroll 8
            for (int k = 0; k < TOPK; ++k) {
                const float vv = ext_v[r][k];                   // LDS broadcast
                const int   hh = ext_i[r][k];
                if (hh < H_LAT) {                               // wave-uniform branch
                    const float4 w4 = *(const float4*)&W_dec[(size_t)hh * D_IN + lane * 4];
                    o.x = fmaf(vv, w4.x, o.x); o.y = fmaf(vv, w4.y, o.y);
                    o.z = fmaf(vv, w4.z, o.z); o.w = fmaf(vv, w4.w, o.w);
                }
            }
            *(float4*)&out[(size_t)(row0 + r) * D_IN + lane * 4] = o;
        }
    }
}

extern "C" void kernel_launch(void* const* d_in, const int* in_sizes, int n_in,
                              void* d_out, int out_size, void* d_ws, size_t ws_size,
                              hipStream_t stream) {
    const float* x     = (const float*)d_in[0];
    const float* W_enc = (const float*)d_in[1];
    const float* b_enc = (const float*)d_in[2];
    const float* W_dec = (const float*)d_in[3];
    const float* b_dec = (const float*)d_in[4];
    float* out = (float*)d_out;

    float* s2w = (float*)d_ws;                                  // 1 float @ offset 0
    unsigned short* Wbf = (unsigned short*)((char*)d_ws + 256); // 4 MB bf16 W_enc

    hipMemsetAsync(d_ws, 0, 256, stream);                       // zero s2w (ws is poisoned)
    conv_kernel<<<dim3(1024), dim3(256), 0, stream>>>(W_enc, Wbf, s2w);
    sae_main<<<dim3(B_TOK / MT), dim3(256), 0, stream>>>(x, W_enc, b_enc, W_dec, b_dec,
                                                         out, Wbf, s2w);
}

// Round 5
// 1303.571 us; speedup vs baseline: 2.0844x; 2.0844x over previous
//
#include <hip/hip_runtime.h>

#define B_TOK 32768
#define D_IN  256
#define H_LAT 8192
#define TOPK  32
#define MT    64          // rows per block
#define NT    128         // h-cols per chunk
#define NCH   (H_LAT / NT)
#define KC    64          // k-slice per A-fragment pass
#define CAP   144         // candidate pool per row (thr=2.3sigma -> lambda~90)
#define XS    264         // xbf row stride (ushort): 132 dw -> 2-way bank alias (free)

typedef __attribute__((ext_vector_type(4))) float f32x4;
typedef __attribute__((ext_vector_type(8))) short bf16x8;

__device__ __forceinline__ unsigned short f2bf(float f) {   // RNE fp32->bf16
    unsigned u = __float_as_uint(f);
    return (unsigned short)((u + 0x7fffu + ((u >> 16) & 1u)) >> 16);
}

// Kernel A: W_enc fp32 -> bf16 into ws; also reduce sum(W^2) -> ws scalar.
__global__ __launch_bounds__(256)
void conv_kernel(const float* __restrict__ W, unsigned short* __restrict__ Wbf,
                 float* __restrict__ s2w) {
    const int total4 = (H_LAT * D_IN) / 4;
    float acc = 0.0f;
    for (int i = blockIdx.x * blockDim.x + threadIdx.x; i < total4;
         i += gridDim.x * blockDim.x) {
        const float4 v = ((const float4*)W)[i];
        acc += v.x * v.x + v.y * v.y + v.z * v.z + v.w * v.w;
        ushort4 o;
        o.x = f2bf(v.x); o.y = f2bf(v.y); o.z = f2bf(v.z); o.w = f2bf(v.w);
        ((ushort4*)Wbf)[i] = o;
    }
#pragma unroll
    for (int off = 32; off > 0; off >>= 1) acc += __shfl_down(acc, off, 64);
    if ((threadIdx.x & 63) == 0) atomicAdd(s2w, acc);
}

// Kernel B: barrier-free bf16-MFMA filter (B direct from global/L2) -> packed
// pool -> wave rank-count top-64 -> exact fp32 rescore of all 64 -> final
// rank top-32 -> decoder. LDS 69.5 KB -> 2 blocks/CU, all 512 blocks resident.
__global__ __launch_bounds__(256, 2)
void sae_main(const float* __restrict__ x, const float* __restrict__ W_enc,
              const float* __restrict__ b_enc, const float* __restrict__ W_dec,
              const float* __restrict__ b_dec, float* __restrict__ out,
              const unsigned short* __restrict__ Wbf, const float* __restrict__ s2w) {
    __shared__ __align__(16) unsigned short xbf[MT][XS];    // 33792 B; ext overlays post-GEMM
    __shared__ unsigned pool[MT][CAP];                      // 36864 B packed (bf16<<13)|(8191-col)
    __shared__ int   cnt[MT];
    __shared__ float thr[MT];

    const int tid  = threadIdx.x;
    const int row0 = blockIdx.x * MT;
    const int wave = tid >> 6, lane = tid & 63;
    const int l15 = lane & 15, quad = lane >> 4;

    if (tid < MT) { cnt[tid] = 0; thr[tid] = 0.0f; }
    __syncthreads();

    // ---- Phase 0: stage (x - b_dec) -> bf16 LDS; per-row sum(x^2) ----
    {
        const int r = tid >> 2, q = tid & 3;                // 4 threads/row, 64 k each
        const float* xr = x + (size_t)(row0 + r) * D_IN + q * 64;
        const float* bd = b_dec + q * 64;
        float s2 = 0.0f;
#pragma unroll
        for (int j = 0; j < 8; ++j) {
            const float4 a = ((const float4*)xr)[2 * j];
            const float4 b = ((const float4*)xr)[2 * j + 1];
            const float4 da = ((const float4*)bd)[2 * j];
            const float4 db = ((const float4*)bd)[2 * j + 1];
            float v[8] = {a.x - da.x, a.y - da.y, a.z - da.z, a.w - da.w,
                          b.x - db.x, b.y - db.y, b.z - db.z, b.w - db.w};
            ushort4 p0, p1;
            p0.x = f2bf(v[0]); p0.y = f2bf(v[1]); p0.z = f2bf(v[2]); p0.w = f2bf(v[3]);
            p1.x = f2bf(v[4]); p1.y = f2bf(v[5]); p1.z = f2bf(v[6]); p1.w = f2bf(v[7]);
#pragma unroll
            for (int e = 0; e < 8; ++e) s2 += v[e] * v[e];
            *(ushort4*)&xbf[r][q * 64 + j * 8]     = p0;
            *(ushort4*)&xbf[r][q * 64 + j * 8 + 4] = p1;
        }
        atomicAdd(&thr[r], s2);
    }
    __syncthreads();
    if (tid < MT) {
        const float s2wm = s2w[0] * (1.0f / ((float)H_LAT * (float)D_IN));
        thr[tid] = 2.3f * sqrtf(s2wm * thr[tid]);
    }
    __syncthreads();

    float thrv[4][4];
#pragma unroll
    for (int mt = 0; mt < 4; ++mt)
#pragma unroll
        for (int qi = 0; qi < 4; ++qi) thrv[mt][qi] = thr[mt * 16 + quad * 4 + qi];

    // ---- Phase 1: barrier-free MFMA filter; wave owns a 32-col strip ----
    const int colbase = wave * 32;
    for (int nc = 0; nc < NCH; ++nc) {
        const int h0 = nc * NT;
        f32x4 acc[4][2];
#pragma unroll
        for (int mt = 0; mt < 4; ++mt)
#pragma unroll
            for (int ct = 0; ct < 2; ++ct) acc[mt][ct] = {0.f, 0.f, 0.f, 0.f};

#pragma unroll
        for (int kc = 0; kc < D_IN / KC; ++kc) {
            bf16x8 a0[4], a1[4];
#pragma unroll
            for (int mt = 0; mt < 4; ++mt) {
                a0[mt] = *(const bf16x8*)&xbf[mt * 16 + l15][kc * KC + quad * 8];
                a1[mt] = *(const bf16x8*)&xbf[mt * 16 + l15][kc * KC + 32 + quad * 8];
            }
#pragma unroll
            for (int ct = 0; ct < 2; ++ct) {
                const unsigned short* bp =
                    Wbf + (size_t)(h0 + colbase + ct * 16 + l15) * D_IN + kc * KC + quad * 8;
                const bf16x8 b0 = *(const bf16x8*)bp;          // direct from L2
                const bf16x8 b1 = *(const bf16x8*)(bp + 32);
#pragma unroll
                for (int mt = 0; mt < 4; ++mt) {
                    acc[mt][ct] = __builtin_amdgcn_mfma_f32_16x16x32_bf16(a0[mt], b0, acc[mt][ct], 0, 0, 0);
                    acc[mt][ct] = __builtin_amdgcn_mfma_f32_16x16x32_bf16(a1[mt], b1, acc[mt][ct], 0, 0, 0);
                }
            }
        }
        // collection (C/D: col=lane&15, row=quad*4+reg); packed 4B entries
#pragma unroll
        for (int ct = 0; ct < 2; ++ct) {
            const int col = h0 + colbase + ct * 16 + l15;
            const float bv = b_enc[col];
#pragma unroll
            for (int mt = 0; mt < 4; ++mt)
#pragma unroll
                for (int qi = 0; qi < 4; ++qi) {
                    const float v = acc[mt][ct][qi] + bv;
                    if (v > thrv[mt][qi]) {
                        const int r = mt * 16 + quad * 4 + qi;
                        const int pos = atomicAdd(&cnt[r], 1);
                        if (pos < CAP)
                            pool[r][pos] = ((unsigned)f2bf(v) << 13) | (unsigned)(8191 - col);
                    }
                }
        }
    }
    __syncthreads();    // pools complete; xbf dead -> ext overlays it

    unsigned short* ext_i = (unsigned short*)&xbf[0][0];        // [MT][64] (8 KB)
    float*          ext_v = (float*)((char*)&xbf[0][0] + MT * 64 * 2); // [MT][64] (16 KB)

    // ---- Phase 2: wave rank-count on packed keys -> top-64 indices ----
    {
        const int rbase = wave * 16;
        for (int rr = 0; rr < 16; ++rr) {
            const int r = rbase + rr;
            const int n = min(cnt[r], CAP);
            if (n <= 128) {                                     // common case (lambda~90)
                unsigned p0 = (lane      < n) ? pool[r][lane]      : (unsigned)(lane + 1);
                unsigned p1 = (lane + 64 < n) ? pool[r][lane + 64] : (unsigned)(lane + 65);
                int r0 = 0, r1 = 0;
                for (int s = 0; s < 64; ++s) {
                    const int src = (lane + s) & 63;
                    const unsigned q0 = (unsigned)__shfl((int)p0, src, 64);
                    const unsigned q1 = (unsigned)__shfl((int)p1, src, 64);
                    r0 += (q0 > p0) + (q1 > p0);
                    r1 += (q0 > p1) + (q1 > p1);
                }
                if (r0 < 64) ext_i[r * 64 + r0] = (p0 >= 8192u)
                    ? (unsigned short)(8191 - (p0 & 0x1fff)) : (unsigned short)(0x2000 + r0);
                if (r1 < 64) ext_i[r * 64 + r1] = (p1 >= 8192u)
                    ? (unsigned short)(8191 - (p1 & 0x1fff)) : (unsigned short)(0x2000 + r1);
            } else {                                            // rare overflow path
                unsigned p[3]; int rk[3] = {0, 0, 0};
#pragma unroll
                for (int e = 0; e < 3; ++e) {
                    const int c = e * 64 + lane;
                    p[e] = (c < n) ? pool[r][c] : (unsigned)(c + 1);
                }
                for (int s = 0; s < 64; ++s) {
                    const int src = (lane + s) & 63;
#pragma unroll
                    for (int e = 0; e < 3; ++e) {
                        const unsigned q = (unsigned)__shfl((int)p[e], src, 64);
#pragma unroll
                        for (int a = 0; a < 3; ++a) rk[a] += (q > p[a]);
                    }
                }
#pragma unroll
                for (int a = 0; a < 3; ++a)
                    if (rk[a] < 64) ext_i[r * 64 + rk[a]] = (p[a] >= 8192u)
                        ? (unsigned short)(8191 - (p[a] & 0x1fff)) : (unsigned short)(0x2000 + rk[a]);
            }
        }
    }
    __syncthreads();

    // ---- Phase 3: exact serial-fmaf fp32 rescore of all 64 (== np oracle) ----
    {
        const int r = tid & 63, c = tid >> 6;                   // 4 threads/row
        const float* xr = x + (size_t)(row0 + r) * D_IN;
        for (int k = 0; k < 16; ++k) {
            const int j = k * 4 + c;
            const int h = ext_i[r * 64 + j];
            float s = 0.0f;
            if (h < H_LAT) {
                const float* wr = W_enc + (size_t)h * D_IN;
                for (int kk = 0; kk < D_IN / 4; ++kk) {         // float4 loads, serial fmaf order
                    const float4 xv = ((const float4*)xr)[kk];
                    const float4 dv = ((const float4*)b_dec)[kk];
                    const float4 wv = ((const float4*)wr)[kk];
                    s = fmaf(xv.x - dv.x, wv.x, s);
                    s = fmaf(xv.y - dv.y, wv.y, s);
                    s = fmaf(xv.z - dv.z, wv.z, s);
                    s = fmaf(xv.w - dv.w, wv.w, s);
                }
                s = fmaxf(s + b_enc[h], 0.0f);
            }
            ext_v[r * 64 + j] = s;
        }
    }
    __syncthreads();

    // ---- Phase 4: final rank on exact values -> top-32 -> decoder ----
    {
        const int rbase = wave * 16;
        const float4 bd4 = *(const float4*)&b_dec[lane * 4];
        for (int rr = 0; rr < 16; ++rr) {
            const int r = rbase + rr;
            const float v = ext_v[r * 64 + lane];
            const int   h = ext_i[r * 64 + lane];
            int rank = 0;
            for (int s = 0; s < 64; ++s) {
                const int src = (lane + s) & 63;
                const float wv = __shfl(v, src, 64);
                const int   wh = __shfl(h, src, 64);
                rank += (wv > v) || (wv == v && wh < h);        // val desc, idx asc; keys unique
            }
            if (rank < TOPK) { ext_v[r * 64 + rank] = v; ext_i[r * 64 + rank] = (unsigned short)h; }
            float4 o = bd4;                                     // wave-in-order: writes visible below
#pragma unroll 8
            for (int k = 0; k < TOPK; ++k) {
                const float vv = ext_v[r * 64 + k];             // LDS broadcast
                const int   hh = ext_i[r * 64 + k];
                if (hh < H_LAT) {                               // guards sentinel (>=0x2000)
                    const float4 w4 = *(const float4*)&W_dec[(size_t)hh * D_IN + lane * 4];
                    o.x = fmaf(vv, w4.x, o.x); o.y = fmaf(vv, w4.y, o.y);
                    o.z = fmaf(vv, w4.z, o.z); o.w = fmaf(vv, w4.w, o.w);
                }
            }
            *(float4*)&out[(size_t)(row0 + r) * D_IN + lane * 4] = o;
        }
    }
}

extern "C" void kernel_launch(void* const* d_in, const int* in_sizes, int n_in,
                              void* d_out, int out_size, void* d_ws, size_t ws_size,
                              hipStream_t stream) {
    const float* x     = (const float*)d_in[0];
    const float* W_enc = (const float*)d_in[1];
    const float* b_enc = (const float*)d_in[2];
    const float* W_dec = (const float*)d_in[3];
    const float* b_dec = (const float*)d_in[4];
    float* out = (float*)d_out;

    float* s2w = (float*)d_ws;                                  // 1 float @ offset 0
    unsigned short* Wbf = (unsigned short*)((char*)d_ws + 256); // 4 MB bf16 W_enc

    hipMemsetAsync(d_ws, 0, 256, stream);                       // zero s2w (ws is poisoned)
    conv_kernel<<<dim3(1024), dim3(256), 0, stream>>>(W_enc, Wbf, s2w);
    sae_main<<<dim3(B_TOK / MT), dim3(256), 0, stream>>>(x, W_enc, b_enc, W_dec, b_dec,
                                                         out, Wbf, s2w);
}

// Round 6
// 800.638 us; speedup vs baseline: 3.3938x; 1.6282x over previous
//
#include <hip/hip_runtime.h>

#define B_TOK 32768
#define D_IN  256
#define H_LAT 8192
#define TOPK  32
#define MT    64          // rows per block
#define NT    128         // h-cols per chunk
#define NCH   (H_LAT / NT)
#define KC    64          // k-slice per A-fragment pass
#define CAP   144         // candidate pool per row (thr=2.3sigma -> lambda~90)
#define XS    264         // xbf row stride (ushort): 132 dw -> 2-way bank alias (free)
#define DELTA 0.016f      // exact-rescore window; ~8 sigma of bf16-GEMM+pack err (~1.8e-3)

typedef __attribute__((ext_vector_type(4))) float f32x4;
typedef __attribute__((ext_vector_type(8))) short bf16x8;

__device__ __forceinline__ unsigned short f2bf(float f) {   // RNE fp32->bf16
    unsigned u = __float_as_uint(f);
    return (unsigned short)((u + 0x7fffu + ((u >> 16) & 1u)) >> 16);
}
__device__ __forceinline__ float bf2f(unsigned short u) {
    return __uint_as_float((unsigned)u << 16);
}

// Kernel A: W_enc fp32 -> bf16 (+ sum W^2); W_dec fp32 -> bf16 (decoder copy).
__global__ __launch_bounds__(256)
void conv_kernel(const float* __restrict__ W, unsigned short* __restrict__ Wbf,
                 float* __restrict__ s2w, const float* __restrict__ Wd,
                 unsigned short* __restrict__ Wdbf) {
    const int total4 = (H_LAT * D_IN) / 4;
    float acc = 0.0f;
    for (int i = blockIdx.x * blockDim.x + threadIdx.x; i < total4;
         i += gridDim.x * blockDim.x) {
        const float4 v = ((const float4*)W)[i];
        acc += v.x * v.x + v.y * v.y + v.z * v.z + v.w * v.w;
        ushort4 o;
        o.x = f2bf(v.x); o.y = f2bf(v.y); o.z = f2bf(v.z); o.w = f2bf(v.w);
        ((ushort4*)Wbf)[i] = o;
    }
    if (Wdbf) {
        for (int i = blockIdx.x * blockDim.x + threadIdx.x; i < total4;
             i += gridDim.x * blockDim.x) {
            const float4 v = ((const float4*)Wd)[i];
            ushort4 o;
            o.x = f2bf(v.x); o.y = f2bf(v.y); o.z = f2bf(v.z); o.w = f2bf(v.w);
            ((ushort4*)Wdbf)[i] = o;
        }
    }
#pragma unroll
    for (int off = 32; off > 0; off >>= 1) acc += __shfl_down(acc, off, 64);
    if ((threadIdx.x & 63) == 0) atomicAdd(s2w, acc);
}

// Kernel B: barrier-free bf16-MFMA filter -> packed pool -> wave rank-count
// top-64 -> exact fp32 rescore of the boundary WINDOW only -> final rank
// top-32 -> bf16 decoder. LDS 69.5 KB -> 2 blocks/CU.
__global__ __launch_bounds__(256, 2)
void sae_main(const float* __restrict__ x, const float* __restrict__ W_enc,
              const float* __restrict__ b_enc, const float* __restrict__ W_dec,
              const float* __restrict__ b_dec, float* __restrict__ out,
              const unsigned short* __restrict__ Wbf, const float* __restrict__ s2w,
              const unsigned short* __restrict__ Wdbf) {
    __shared__ __align__(16) unsigned short xbf[MT][XS];    // 33792 B; ext overlays post-GEMM
    __shared__ unsigned pool[MT][CAP];                      // 36864 B packed (bf16<<13)|(8191-col)
    __shared__ int   cnt[MT];
    __shared__ float thr[MT];

    const int tid  = threadIdx.x;
    const int row0 = blockIdx.x * MT;
    const int wave = tid >> 6, lane = tid & 63;
    const int l15 = lane & 15, quad = lane >> 4;

    if (tid < MT) { cnt[tid] = 0; thr[tid] = 0.0f; }
    __syncthreads();

    // ---- Phase 0: stage (x - b_dec) -> bf16 LDS; per-row sum(x^2) ----
    {
        const int r = tid >> 2, q = tid & 3;                // 4 threads/row, 64 k each
        const float* xr = x + (size_t)(row0 + r) * D_IN + q * 64;
        const float* bd = b_dec + q * 64;
        float s2 = 0.0f;
#pragma unroll
        for (int j = 0; j < 8; ++j) {
            const float4 a = ((const float4*)xr)[2 * j];
            const float4 b = ((const float4*)xr)[2 * j + 1];
            const float4 da = ((const float4*)bd)[2 * j];
            const float4 db = ((const float4*)bd)[2 * j + 1];
            float v[8] = {a.x - da.x, a.y - da.y, a.z - da.z, a.w - da.w,
                          b.x - db.x, b.y - db.y, b.z - db.z, b.w - db.w};
            ushort4 p0, p1;
            p0.x = f2bf(v[0]); p0.y = f2bf(v[1]); p0.z = f2bf(v[2]); p0.w = f2bf(v[3]);
            p1.x = f2bf(v[4]); p1.y = f2bf(v[5]); p1.z = f2bf(v[6]); p1.w = f2bf(v[7]);
#pragma unroll
            for (int e = 0; e < 8; ++e) s2 += v[e] * v[e];
            *(ushort4*)&xbf[r][q * 64 + j * 8]     = p0;
            *(ushort4*)&xbf[r][q * 64 + j * 8 + 4] = p1;
        }
        atomicAdd(&thr[r], s2);
    }
    __syncthreads();
    if (tid < MT) {
        const float s2wm = s2w[0] * (1.0f / ((float)H_LAT * (float)D_IN));
        thr[tid] = 2.3f * sqrtf(s2wm * thr[tid]);
    }
    __syncthreads();

    float thrv[4][4];
#pragma unroll
    for (int mt = 0; mt < 4; ++mt)
#pragma unroll
        for (int qi = 0; qi < 4; ++qi) thrv[mt][qi] = thr[mt * 16 + quad * 4 + qi];

    // ---- Phase 1: barrier-free MFMA filter; wave owns a 32-col strip ----
    const int colbase = wave * 32;
    for (int nc = 0; nc < NCH; ++nc) {
        const int h0 = nc * NT;
        f32x4 acc[4][2];
#pragma unroll
        for (int mt = 0; mt < 4; ++mt)
#pragma unroll
            for (int ct = 0; ct < 2; ++ct) acc[mt][ct] = {0.f, 0.f, 0.f, 0.f};

#pragma unroll
        for (int kc = 0; kc < D_IN / KC; ++kc) {
            bf16x8 a0[4], a1[4];
#pragma unroll
            for (int mt = 0; mt < 4; ++mt) {
                a0[mt] = *(const bf16x8*)&xbf[mt * 16 + l15][kc * KC + quad * 8];
                a1[mt] = *(const bf16x8*)&xbf[mt * 16 + l15][kc * KC + 32 + quad * 8];
            }
#pragma unroll
            for (int ct = 0; ct < 2; ++ct) {
                const unsigned short* bp =
                    Wbf + (size_t)(h0 + colbase + ct * 16 + l15) * D_IN + kc * KC + quad * 8;
                const bf16x8 b0 = *(const bf16x8*)bp;          // direct from L2
                const bf16x8 b1 = *(const bf16x8*)(bp + 32);
#pragma unroll
                for (int mt = 0; mt < 4; ++mt) {
                    acc[mt][ct] = __builtin_amdgcn_mfma_f32_16x16x32_bf16(a0[mt], b0, acc[mt][ct], 0, 0, 0);
                    acc[mt][ct] = __builtin_amdgcn_mfma_f32_16x16x32_bf16(a1[mt], b1, acc[mt][ct], 0, 0, 0);
                }
            }
        }
        // collection (C/D: col=lane&15, row=quad*4+reg); packed 4B entries
#pragma unroll
        for (int ct = 0; ct < 2; ++ct) {
            const int col = h0 + colbase + ct * 16 + l15;
            const float bv = b_enc[col];
#pragma unroll
            for (int mt = 0; mt < 4; ++mt)
#pragma unroll
                for (int qi = 0; qi < 4; ++qi) {
                    const float v = acc[mt][ct][qi] + bv;
                    if (v > thrv[mt][qi]) {
                        const int r = mt * 16 + quad * 4 + qi;
                        const int pos = atomicAdd(&cnt[r], 1);
                        if (pos < CAP)
                            pool[r][pos] = ((unsigned)f2bf(v) << 13) | (unsigned)(8191 - col);
                    }
                }
        }
    }
    __syncthreads();    // pools complete; xbf dead -> ext overlays it

    unsigned short* ext_i = (unsigned short*)&xbf[0][0];        // [MT][64] (8 KB)
    float*          ext_v = (float*)((char*)&xbf[0][0] + MT * 64 * 2); // [MT][64] (16 KB)

    // ---- Phase 2: wave rank-count on packed keys -> top-64 (idx + approx val) ----
    {
        const int rbase = wave * 16;
        for (int rr = 0; rr < 16; ++rr) {
            const int r = rbase + rr;
            const int n = min(cnt[r], CAP);
            unsigned p[3]; int rk[3];
            const int S = (n <= 128) ? 2 : 3;                   // wave-uniform
#pragma unroll
            for (int e = 0; e < 3; ++e) {
                const int c = e * 64 + lane;
                p[e] = (c < n) ? pool[r][c] : (unsigned)(c + 1);  // unique tiny sentinels
                rk[e] = 0;
            }
            if (S == 2) {
                for (int s = 0; s < 64; ++s) {
                    const int src = (lane + s) & 63;
                    const unsigned q0 = (unsigned)__shfl((int)p[0], src, 64);
                    const unsigned q1 = (unsigned)__shfl((int)p[1], src, 64);
                    rk[0] += (q0 > p[0]) + (q1 > p[0]);
                    rk[1] += (q0 > p[1]) + (q1 > p[1]);
                }
            } else {
                for (int s = 0; s < 64; ++s) {
                    const int src = (lane + s) & 63;
#pragma unroll
                    for (int e = 0; e < 3; ++e) {
                        const unsigned q = (unsigned)__shfl((int)p[e], src, 64);
#pragma unroll
                        for (int a = 0; a < 3; ++a) rk[a] += (q > p[a]);
                    }
                }
            }
#pragma unroll
            for (int e = 0; e < 3; ++e) {
                if (e < S && rk[e] < 64) {
                    if (p[e] >= 8192u) {                        // real entry (val>thr -> big key)
                        ext_i[r * 64 + rk[e]] = (unsigned short)(8191 - (p[e] & 0x1fffu));
                        ext_v[r * 64 + rk[e]] = __uint_as_float((p[e] >> 13) << 16);
                    } else {                                    // filler: unique sentinel, val 0
                        ext_i[r * 64 + rk[e]] = (unsigned short)(0x2000 + rk[e]);
                        ext_v[r * 64 + rk[e]] = 0.0f;
                    }
                }
            }
        }
    }
    __syncthreads();

    // ---- Phase 3: exact serial-fmaf rescore of the boundary window only ----
    {
        const int r = tid & 63, c = tid >> 6;                   // 4 threads/row
        const float v32 = ext_v[r * 64 + TOPK - 1];             // approx 32nd value
        __syncthreads();                                        // all read v32 before any writes
        const float* xr = x + (size_t)(row0 + r) * D_IN;
        for (int j = c; j < 64; j += 4) {
            const float va = ext_v[r * 64 + j];
            const int   h  = ext_i[r * 64 + j];
            if (h < H_LAT && fabsf(va - v32) <= DELTA) {
                const float* wr = W_enc + (size_t)h * D_IN;
                float s = 0.0f;
                for (int kk = 0; kk < D_IN / 4; ++kk) {         // serial fmaf == np oracle
                    const float4 xv = ((const float4*)xr)[kk];
                    const float4 dv = ((const float4*)b_dec)[kk];
                    const float4 wv = ((const float4*)wr)[kk];
                    s = fmaf(xv.x - dv.x, wv.x, s);
                    s = fmaf(xv.y - dv.y, wv.y, s);
                    s = fmaf(xv.z - dv.z, wv.z, s);
                    s = fmaf(xv.w - dv.w, wv.w, s);
                }
                ext_v[r * 64 + j] = fmaxf(s + b_enc[h], 0.0f);
            }
        }
    }
    __syncthreads();

    // ---- Phase 4: final rank -> top-32 -> decoder (bf16 W_dec if available) ----
    {
        const int rbase = wave * 16;
        const bool usebf = (Wdbf != nullptr);
        const float4 bd4 = *(const float4*)&b_dec[lane * 4];
        for (int rr = 0; rr < 16; ++rr) {
            const int r = rbase + rr;
            const float v = ext_v[r * 64 + lane];
            const int   h = ext_i[r * 64 + lane];
            int rank = 0;
            for (int s = 0; s < 64; ++s) {
                const int src = (lane + s) & 63;
                const float wv = __shfl(v, src, 64);
                const int   wh = __shfl(h, src, 64);
                rank += (wv > v) || (wv == v && wh < h);        // val desc, idx asc; keys unique
            }
            if (rank < TOPK) { ext_v[r * 64 + rank] = v; ext_i[r * 64 + rank] = (unsigned short)h; }
            float4 o = bd4;                                     // wave-in-order: writes visible below
#pragma unroll 8
            for (int k = 0; k < TOPK; ++k) {
                const float vv = ext_v[r * 64 + k];             // LDS broadcast
                const int   hh = ext_i[r * 64 + k];
                if (hh < H_LAT) {                               // wave-uniform (guards sentinel)
                    if (usebf) {
                        const ushort4 w = *(const ushort4*)&Wdbf[(size_t)hh * D_IN + lane * 4];
                        o.x = fmaf(vv, bf2f(w.x), o.x); o.y = fmaf(vv, bf2f(w.y), o.y);
                        o.z = fmaf(vv, bf2f(w.z), o.z); o.w = fmaf(vv, bf2f(w.w), o.w);
                    } else {
                        const float4 w4 = *(const float4*)&W_dec[(size_t)hh * D_IN + lane * 4];
                        o.x = fmaf(vv, w4.x, o.x); o.y = fmaf(vv, w4.y, o.y);
                        o.z = fmaf(vv, w4.z, o.z); o.w = fmaf(vv, w4.w, o.w);
                    }
                }
            }
            *(float4*)&out[(size_t)(row0 + r) * D_IN + lane * 4] = o;
        }
    }
}

extern "C" void kernel_launch(void* const* d_in, const int* in_sizes, int n_in,
                              void* d_out, int out_size, void* d_ws, size_t ws_size,
                              hipStream_t stream) {
    const float* x     = (const float*)d_in[0];
    const float* W_enc = (const float*)d_in[1];
    const float* b_enc = (const float*)d_in[2];
    const float* W_dec = (const float*)d_in[3];
    const float* b_dec = (const float*)d_in[4];
    float* out = (float*)d_out;

    const size_t wel = (size_t)H_LAT * D_IN;                    // 2M elements
    float* s2w = (float*)d_ws;                                  // 1 float @ offset 0
    unsigned short* Wbf  = (unsigned short*)((char*)d_ws + 256);        // 4 MB bf16 W_enc
    unsigned short* Wdbf = (ws_size >= 256 + 2 * wel * sizeof(unsigned short))
                         ? Wbf + wel : nullptr;                 // 4 MB bf16 W_dec

    hipMemsetAsync(d_ws, 0, 256, stream);                       // zero s2w (ws is poisoned)
    conv_kernel<<<dim3(1024), dim3(256), 0, stream>>>(W_enc, Wbf, s2w, W_dec, Wdbf);
    sae_main<<<dim3(B_TOK / MT), dim3(256), 0, stream>>>(x, W_enc, b_enc, W_dec, b_dec,
                                                         out, Wbf, s2w, Wdbf);
}

// Round 7
// 757.199 us; speedup vs baseline: 3.5885x; 1.0574x over previous
//
#include <hip/hip_runtime.h>

#define B_TOK 32768
#define D_IN  256
#define H_LAT 8192
#define TOPK  32
#define MT    64          // rows per block
#define NT    128         // h-cols per chunk
#define NCH   (H_LAT / NT)
#define CAP   144         // candidate pool per row (thr=2.3sigma -> lambda~90)
#define XS    264         // xbf row stride (ushort): 132 dw -> 2-way bank alias (free)
#define DELTA 0.016f      // exact-rescore window; ~8 sigma of bf16-GEMM+pack err (~1.8e-3)

typedef __attribute__((ext_vector_type(4))) float f32x4;
typedef __attribute__((ext_vector_type(8))) short bf16x8;

__device__ __forceinline__ unsigned short f2bf(float f) {   // RNE fp32->bf16
    unsigned u = __float_as_uint(f);
    return (unsigned short)((u + 0x7fffu + ((u >> 16) & 1u)) >> 16);
}
__device__ __forceinline__ float bf2f(unsigned short u) {
    return __uint_as_float((unsigned)u << 16);
}

// Kernel A: W_enc fp32 -> bf16 (+ sum W^2); W_dec fp32 -> bf16 (decoder copy).
__global__ __launch_bounds__(256)
void conv_kernel(const float* __restrict__ W, unsigned short* __restrict__ Wbf,
                 float* __restrict__ s2w, const float* __restrict__ Wd,
                 unsigned short* __restrict__ Wdbf) {
    const int total4 = (H_LAT * D_IN) / 4;
    float acc = 0.0f;
    for (int i = blockIdx.x * blockDim.x + threadIdx.x; i < total4;
         i += gridDim.x * blockDim.x) {
        const float4 v = ((const float4*)W)[i];
        acc += v.x * v.x + v.y * v.y + v.z * v.z + v.w * v.w;
        ushort4 o;
        o.x = f2bf(v.x); o.y = f2bf(v.y); o.z = f2bf(v.z); o.w = f2bf(v.w);
        ((ushort4*)Wbf)[i] = o;
    }
    for (int i = blockIdx.x * blockDim.x + threadIdx.x; i < total4;
         i += gridDim.x * blockDim.x) {
        const float4 v = ((const float4*)Wd)[i];
        ushort4 o;
        o.x = f2bf(v.x); o.y = f2bf(v.y); o.z = f2bf(v.z); o.w = f2bf(v.w);
        ((ushort4*)Wdbf)[i] = o;
    }
#pragma unroll
    for (int off = 32; off > 0; off >>= 1) acc += __shfl_down(acc, off, 64);
    if ((threadIdx.x & 63) == 0) atomicAdd(s2w, acc);
}

// Kernel B: A-in-registers barrier-free bf16-MFMA filter (zero LDS traffic in
// the K-loop; B direct from L2) -> packed pool -> wave rank-count top-64 ->
// exact fp32 rescore of boundary window -> final rank top-32 -> bf16 decoder.
__global__ __launch_bounds__(256, 2)
void sae_main(const float* __restrict__ x, const float* __restrict__ W_enc,
              const float* __restrict__ b_enc, const float* __restrict__ W_dec,
              const float* __restrict__ b_dec, float* __restrict__ out,
              const unsigned short* __restrict__ Wbf, const float* __restrict__ s2w,
              const unsigned short* __restrict__ Wdbf) {
    __shared__ __align__(16) unsigned short xbf[MT][XS];    // 33792 B; ext overlays post-GEMM
    __shared__ unsigned pool[MT][CAP];                      // 36864 B packed (bf16<<13)|(8191-col)
    __shared__ int   cnt[MT];
    __shared__ float thr[MT];

    const int tid  = threadIdx.x;
    const int row0 = blockIdx.x * MT;
    const int wave = tid >> 6, lane = tid & 63;
    const int l15 = lane & 15, quad = lane >> 4;

    if (tid < MT) { cnt[tid] = 0; thr[tid] = 0.0f; }
    __syncthreads();

    // ---- Phase 0: stage (x - b_dec) -> bf16 LDS; per-row sum(x^2) ----
    {
        const int r = tid >> 2, q = tid & 3;                // 4 threads/row, 64 k each
        const float* xr = x + (size_t)(row0 + r) * D_IN + q * 64;
        const float* bd = b_dec + q * 64;
        float s2 = 0.0f;
#pragma unroll
        for (int j = 0; j < 8; ++j) {
            const float4 a = ((const float4*)xr)[2 * j];
            const float4 b = ((const float4*)xr)[2 * j + 1];
            const float4 da = ((const float4*)bd)[2 * j];
            const float4 db = ((const float4*)bd)[2 * j + 1];
            float v[8] = {a.x - da.x, a.y - da.y, a.z - da.z, a.w - da.w,
                          b.x - db.x, b.y - db.y, b.z - db.z, b.w - db.w};
            ushort4 p0, p1;
            p0.x = f2bf(v[0]); p0.y = f2bf(v[1]); p0.z = f2bf(v[2]); p0.w = f2bf(v[3]);
            p1.x = f2bf(v[4]); p1.y = f2bf(v[5]); p1.z = f2bf(v[6]); p1.w = f2bf(v[7]);
#pragma unroll
            for (int e = 0; e < 8; ++e) s2 += v[e] * v[e];
            *(ushort4*)&xbf[r][q * 64 + j * 8]     = p0;
            *(ushort4*)&xbf[r][q * 64 + j * 8 + 4] = p1;
        }
        atomicAdd(&thr[r], s2);
    }
    __syncthreads();
    if (tid < MT) {
        const float s2wm = s2w[0] * (1.0f / ((float)H_LAT * (float)D_IN));
        thr[tid] = 2.3f * sqrtf(s2wm * thr[tid]);
    }
    __syncthreads();

    float thrv[4][4];
#pragma unroll
    for (int mt = 0; mt < 4; ++mt)
#pragma unroll
        for (int qi = 0; qi < 4; ++qi) thrv[mt][qi] = thr[mt * 16 + quad * 4 + qi];

    // ---- One-time: load this wave's ENTIRE A operand into registers ----
    // Fragment for K-chunk c8: A[m=l15][k=c8*32+quad*8+j], j=0..7. 128 VGPRs.
    bf16x8 areg[4][8];
#pragma unroll
    for (int mt = 0; mt < 4; ++mt)
#pragma unroll
        for (int c8 = 0; c8 < 8; ++c8)
            areg[mt][c8] = *(const bf16x8*)&xbf[mt * 16 + l15][c8 * 32 + quad * 8];

    // ---- Phase 1: barrier-free, LDS-free MFMA K-loop; wave owns 32-col strip ----
    const int colbase = wave * 32;
    for (int nc = 0; nc < NCH; ++nc) {
        const int h0 = nc * NT;
        // prefetch bias for this strip (in flight during the MFMAs)
        float bv[2];
#pragma unroll
        for (int ct = 0; ct < 2; ++ct) bv[ct] = b_enc[h0 + colbase + ct * 16 + l15];

        f32x4 acc[4][2];
#pragma unroll
        for (int mt = 0; mt < 4; ++mt)
#pragma unroll
            for (int ct = 0; ct < 2; ++ct) acc[mt][ct] = {0.f, 0.f, 0.f, 0.f};

#pragma unroll
        for (int c8 = 0; c8 < 8; ++c8) {
#pragma unroll
            for (int ct = 0; ct < 2; ++ct) {
                const unsigned short* bp =
                    Wbf + (size_t)(h0 + colbase + ct * 16 + l15) * D_IN + c8 * 32 + quad * 8;
                const bf16x8 b = *(const bf16x8*)bp;           // direct from L2
#pragma unroll
                for (int mt = 0; mt < 4; ++mt)
                    acc[mt][ct] = __builtin_amdgcn_mfma_f32_16x16x32_bf16(areg[mt][c8], b, acc[mt][ct], 0, 0, 0);
            }
        }
        // collection (C/D: col=lane&15, row=quad*4+reg); packed 4B entries
#pragma unroll
        for (int ct = 0; ct < 2; ++ct) {
            const int col = h0 + colbase + ct * 16 + l15;
#pragma unroll
            for (int mt = 0; mt < 4; ++mt)
#pragma unroll
                for (int qi = 0; qi < 4; ++qi) {
                    const float v = acc[mt][ct][qi] + bv[ct];
                    if (v > thrv[mt][qi]) {
                        const int r = mt * 16 + quad * 4 + qi;
                        const int pos = atomicAdd(&cnt[r], 1);
                        if (pos < CAP)
                            pool[r][pos] = ((unsigned)f2bf(v) << 13) | (unsigned)(8191 - col);
                    }
                }
        }
    }
    __syncthreads();    // pools complete; xbf dead -> ext overlays it

    unsigned short* ext_i = (unsigned short*)&xbf[0][0];        // [MT][64] (8 KB)
    float*          ext_v = (float*)((char*)&xbf[0][0] + MT * 64 * 2); // [MT][64] (16 KB)

    // ---- Phase 2: wave rank-count on packed keys -> top-64 (idx + approx val) ----
    {
        const int rbase = wave * 16;
        for (int rr = 0; rr < 16; ++rr) {
            const int r = rbase + rr;
            const int n = min(cnt[r], CAP);
            unsigned p[3]; int rk[3];
            const int S = (n <= 128) ? 2 : 3;                   // wave-uniform
#pragma unroll
            for (int e = 0; e < 3; ++e) {
                const int c = e * 64 + lane;
                p[e] = (c < n) ? pool[r][c] : (unsigned)(c + 1);  // unique tiny sentinels
                rk[e] = 0;
            }
            if (S == 2) {
                for (int s = 0; s < 64; ++s) {
                    const int src = (lane + s) & 63;
                    const unsigned q0 = (unsigned)__shfl((int)p[0], src, 64);
                    const unsigned q1 = (unsigned)__shfl((int)p[1], src, 64);
                    rk[0] += (q0 > p[0]) + (q1 > p[0]);
                    rk[1] += (q0 > p[1]) + (q1 > p[1]);
                }
            } else {
                for (int s = 0; s < 64; ++s) {
                    const int src = (lane + s) & 63;
#pragma unroll
                    for (int e = 0; e < 3; ++e) {
                        const unsigned q = (unsigned)__shfl((int)p[e], src, 64);
#pragma unroll
                        for (int a = 0; a < 3; ++a) rk[a] += (q > p[a]);
                    }
                }
            }
#pragma unroll
            for (int e = 0; e < 3; ++e) {
                if (e < S && rk[e] < 64) {
                    if (p[e] >= 8192u) {                        // real entry (val>thr -> big key)
                        ext_i[r * 64 + rk[e]] = (unsigned short)(8191 - (p[e] & 0x1fffu));
                        ext_v[r * 64 + rk[e]] = __uint_as_float((p[e] >> 13) << 16);
                    } else {                                    // filler: unique sentinel, val 0
                        ext_i[r * 64 + rk[e]] = (unsigned short)(0x2000 + rk[e]);
                        ext_v[r * 64 + rk[e]] = 0.0f;
                    }
                }
            }
        }
    }
    __syncthreads();

    // ---- Phase 3: exact serial-fmaf rescore of the boundary window only ----
    {
        const int r = tid & 63, c = tid >> 6;                   // 4 threads/row
        const float v32 = ext_v[r * 64 + TOPK - 1];             // approx 32nd value
        __syncthreads();                                        // all read v32 before any writes
        const float* xr = x + (size_t)(row0 + r) * D_IN;
        for (int j = c; j < 64; j += 4) {
            const float va = ext_v[r * 64 + j];
            const int   h  = ext_i[r * 64 + j];
            if (h < H_LAT && fabsf(va - v32) <= DELTA) {
                const float* wr = W_enc + (size_t)h * D_IN;
                float s = 0.0f;
                for (int kk = 0; kk < D_IN / 4; ++kk) {         // serial fmaf == np oracle
                    const float4 xv = ((const float4*)xr)[kk];
                    const float4 dv = ((const float4*)b_dec)[kk];
                    const float4 wv = ((const float4*)wr)[kk];
                    s = fmaf(xv.x - dv.x, wv.x, s);
                    s = fmaf(xv.y - dv.y, wv.y, s);
                    s = fmaf(xv.z - dv.z, wv.z, s);
                    s = fmaf(xv.w - dv.w, wv.w, s);
                }
                ext_v[r * 64 + j] = fmaxf(s + b_enc[h], 0.0f);
            }
        }
    }
    __syncthreads();

    // ---- Phase 4: final rank -> top-32 -> bf16 decoder ----
    {
        const int rbase = wave * 16;
        const float4 bd4 = *(const float4*)&b_dec[lane * 4];
        for (int rr = 0; rr < 16; ++rr) {
            const int r = rbase + rr;
            const float v = ext_v[r * 64 + lane];
            const int   h = ext_i[r * 64 + lane];
            int rank = 0;
            for (int s = 0; s < 64; ++s) {
                const int src = (lane + s) & 63;
                const float wv = __shfl(v, src, 64);
                const int   wh = __shfl(h, src, 64);
                rank += (wv > v) || (wv == v && wh < h);        // val desc, idx asc; keys unique
            }
            if (rank < TOPK) { ext_v[r * 64 + rank] = v; ext_i[r * 64 + rank] = (unsigned short)h; }
            float4 o = bd4;                                     // wave-in-order: writes visible below
#pragma unroll 8
            for (int k = 0; k < TOPK; ++k) {
                const float vv = ext_v[r * 64 + k];             // LDS broadcast
                const int   hh = ext_i[r * 64 + k];
                if (hh < H_LAT) {                               // wave-uniform (guards sentinel)
                    const ushort4 w = *(const ushort4*)&Wdbf[(size_t)hh * D_IN + lane * 4];
                    o.x = fmaf(vv, bf2f(w.x), o.x); o.y = fmaf(vv, bf2f(w.y), o.y);
                    o.z = fmaf(vv, bf2f(w.z), o.z); o.w = fmaf(vv, bf2f(w.w), o.w);
                }
            }
            *(float4*)&out[(size_t)(row0 + r) * D_IN + lane * 4] = o;
        }
    }
}

extern "C" void kernel_launch(void* const* d_in, const int* in_sizes, int n_in,
                              void* d_out, int out_size, void* d_ws, size_t ws_size,
                              hipStream_t stream) {
    const float* x     = (const float*)d_in[0];
    const float* W_enc = (const float*)d_in[1];
    const float* b_enc = (const float*)d_in[2];
    const float* W_dec = (const float*)d_in[3];
    const float* b_dec = (const float*)d_in[4];
    float* out = (float*)d_out;

    const size_t wel = (size_t)H_LAT * D_IN;                    // 2M elements
    float* s2w = (float*)d_ws;                                  // 1 float @ offset 0
    unsigned short* Wbf  = (unsigned short*)((char*)d_ws + 256); // 4 MB bf16 W_enc
    unsigned short* Wdbf = Wbf + wel;                            // 4 MB bf16 W_dec

    hipMemsetAsync(d_ws, 0, 256, stream);                       // zero s2w (ws is poisoned)
    conv_kernel<<<dim3(1024), dim3(256), 0, stream>>>(W_enc, Wbf, s2w, W_dec, Wdbf);
    sae_main<<<dim3(B_TOK / MT), dim3(256), 0, stream>>>(x, W_enc, b_enc, W_dec, b_dec,
                                                         out, Wbf, s2w, Wdbf);
}